// Round 2
// baseline (411.885 us; speedup 1.0000x reference)
//
#include <hip/hip_runtime.h>

// Causal linear attention (ELU+1 feature map), chunked prefix-scan formulation.
// Shapes: q,k,v,out = [B=2, T=2048, H=16, D=64] fp32, layout [B,T,H,D].
//
// out_t = phi(q_t) . S_t / (phi(q_t) . z_t + EPS)
//   S_t = sum_{s<=t} phi(k_s)^T v_s   (D x D per (b,h))
//   z_t = sum_{s<=t} phi(k_s)
//
// Chunked (C=64): per chunk c,
//   S_prev/z_prev = exclusive prefix over chunk deltas  (phase 1 + phase 2)
//   out = (phi(Q) @ S_prev + tril(phiQ phiK^T) @ V) / (phiQ.z_prev + rowsum + EPS)

#define BQ 2
#define TT 2048
#define HH 16
#define DD 64
#define CC 64
#define NC (TT / CC)      // 32 chunks per (b,h)
#define BH (BQ * HH)      // 32
#define NCH (BH * NC)     // 1024 chunk-blocks
#define LDP 68            // LDS row stride (floats): 16B-aligned, breaks pow2 strides

#define F4C(v, i) ((i) == 0 ? (v).x : (i) == 1 ? (v).y : (i) == 2 ? (v).z : (v).w)

__device__ __forceinline__ float phi_f(float x) {
    return x > 0.f ? x + 1.f : __expf(x);   // elu(x)+1
}

// ---------------- Phase 1: per-chunk state deltas ----------------
__global__ __launch_bounds__(256) void k_state(const float* __restrict__ K,
                                               const float* __restrict__ V,
                                               float* __restrict__ wsS,
                                               float* __restrict__ wsZ) {
    __shared__ float pk[CC][LDP];
    __shared__ float pv[CC][LDP];

    const int cid = blockIdx.x;
    const int bh = cid / NC, c = cid % NC;
    const int b = bh / HH, h = bh % HH;
    const int t0 = c * CC;
    const int tid = threadIdx.x;

#pragma unroll
    for (int w = 0; w < 4; ++w) {
        const int idx = tid + (w << 8);
        const int r = idx >> 4, q4 = (idx & 15) << 2;
        const int g = (((b * TT + t0 + r) * HH + h) << 6) + q4;
        float4 kv = *(const float4*)(K + g);
        kv.x = phi_f(kv.x); kv.y = phi_f(kv.y); kv.z = phi_f(kv.z); kv.w = phi_f(kv.w);
        *(float4*)&pk[r][q4] = kv;
        *(float4*)&pv[r][q4] = *(const float4*)(V + g);
    }
    __syncthreads();

    const int d0 = (tid >> 4) << 2;   // deltaS rows this thread owns
    const int e0 = (tid & 15) << 2;   // deltaS cols this thread owns
    float acc[4][4] = {};
    float zac[4] = {};
#pragma unroll 8
    for (int t = 0; t < CC; ++t) {
        const float4 a = *(const float4*)&pk[t][d0];
        const float4 vb = *(const float4*)&pv[t][e0];
        acc[0][0] += a.x * vb.x; acc[0][1] += a.x * vb.y; acc[0][2] += a.x * vb.z; acc[0][3] += a.x * vb.w;
        acc[1][0] += a.y * vb.x; acc[1][1] += a.y * vb.y; acc[1][2] += a.y * vb.z; acc[1][3] += a.y * vb.w;
        acc[2][0] += a.z * vb.x; acc[2][1] += a.z * vb.y; acc[2][2] += a.z * vb.z; acc[2][3] += a.z * vb.w;
        acc[3][0] += a.w * vb.x; acc[3][1] += a.w * vb.y; acc[3][2] += a.w * vb.z; acc[3][3] += a.w * vb.w;
        zac[0] += a.x; zac[1] += a.y; zac[2] += a.z; zac[3] += a.w;
    }

    float* S = wsS + (size_t)cid * (DD * DD);
#pragma unroll
    for (int i = 0; i < 4; ++i)
        *(float4*)(S + (d0 + i) * DD + e0) =
            make_float4(acc[i][0], acc[i][1], acc[i][2], acc[i][3]);
    if (e0 == 0)
        *(float4*)(wsZ + cid * DD + d0) = make_float4(zac[0], zac[1], zac[2], zac[3]);
}

// ---------------- Phase 2: exclusive prefix over chunks ----------------
__global__ __launch_bounds__(256) void k_scan(float* __restrict__ wsS,
                                              float* __restrict__ wsZ) {
    const int blk = blockIdx.x, tid = threadIdx.x;
    if (blk < 512) {                       // S: 32 bh * 16 segments of 256 elems
        const int bh = blk >> 4;
        const int off = ((blk & 15) << 8) + tid;
        float* p = wsS + (size_t)bh * NC * (DD * DD) + off;
        float run = 0.f;
#pragma unroll
        for (int c = 0; c < NC; ++c) {
            const float d = p[(size_t)c * (DD * DD)];
            p[(size_t)c * (DD * DD)] = run;
            run += d;
        }
    } else {                               // z: 32 bh * 64 = 2048 elems, 8 blocks
        const int zi = ((blk - 512) << 8) + tid;
        const int bh = zi >> 6, d = zi & 63;
        float* p = wsZ + bh * NC * DD + d;
        float run = 0.f;
#pragma unroll
        for (int c = 0; c < NC; ++c) {
            const float dv = p[c * DD];
            p[c * DD] = run;
            run += dv;
        }
    }
}

// ---------------- Phase 3: outputs ----------------
__global__ __launch_bounds__(256) void k_out(const float* __restrict__ Q,
                                             const float* __restrict__ K,
                                             const float* __restrict__ V,
                                             const float* __restrict__ wsS,
                                             const float* __restrict__ wsZ,
                                             float* __restrict__ O) {
    __shared__ float bufA[CC][LDP];   // phi(Q), later V
    __shared__ float bufB[CC][LDP];   // phi(K), later A = tril(phiQ phiK^T)
    __shared__ float Sp[DD * DD];     // S_prev
    __shared__ float zp[DD];          // z_prev
    __shared__ float denA[CC];        // intra-chunk denominator per row

    const int cid = blockIdx.x;
    const int bh = cid / NC, c = cid % NC;
    const int b = bh / HH, h = bh % HH;
    const int t0 = c * CC;
    const int tid = threadIdx.x;

    float4 vreg[4];                    // V staged in regs, LDS-written later (T14)
#pragma unroll
    for (int w = 0; w < 4; ++w) {
        const int idx = tid + (w << 8);
        const int r = idx >> 4, q4 = (idx & 15) << 2;
        const int g = (((b * TT + t0 + r) * HH + h) << 6) + q4;
        vreg[w] = *(const float4*)(V + g);
        float4 qv = *(const float4*)(Q + g);
        qv.x = phi_f(qv.x); qv.y = phi_f(qv.y); qv.z = phi_f(qv.z); qv.w = phi_f(qv.w);
        *(float4*)&bufA[r][q4] = qv;
        float4 kv = *(const float4*)(K + g);
        kv.x = phi_f(kv.x); kv.y = phi_f(kv.y); kv.z = phi_f(kv.z); kv.w = phi_f(kv.w);
        *(float4*)&bufB[r][q4] = kv;
    }
    {
        const float4* Sg = (const float4*)(wsS + (size_t)cid * (DD * DD));
        float4* Sl = (float4*)Sp;
#pragma unroll
        for (int w = 0; w < 4; ++w) Sl[tid + (w << 8)] = Sg[tid + (w << 8)];
        if (tid < 16) ((float4*)zp)[tid] = ((const float4*)(wsZ + cid * DD))[tid];
    }
    __syncthreads();

    const int tt = (tid >> 4) << 2;   // output row-tile base (4 rows)
    const int e0 = (tid & 15) << 2;   // output col-tile base (4 cols); s-tile in pass A

    // ---- Fused pass: one sweep over d loads each phiQ row-quad ONCE and feeds
    //   (a) A[tt+i][e0+j] += qr[i] . kr[j]         (intra-chunk scores)
    //   (b) o[i][:]       += qr[i] row x S_prev     (inter-chunk numerator)
    //   (c) dint[i]       += qr[i] . z_prev         (inter-chunk denominator)
    float a[4][4] = {};
    float o[4][4] = {};
    float dint[4] = {};
#pragma unroll
    for (int d = 0; d < DD; d += 4) {
        float4 qr[4], kr[4], sr[4];
#pragma unroll
        for (int i = 0; i < 4; ++i) qr[i] = *(const float4*)&bufA[tt + i][d];
#pragma unroll
        for (int j = 0; j < 4; ++j) kr[j] = *(const float4*)&bufB[e0 + j][d];
#pragma unroll
        for (int r = 0; r < 4; ++r) sr[r] = *(const float4*)&Sp[(d + r) * DD + e0];
        const float4 z4 = *(const float4*)&zp[d];
#pragma unroll
        for (int i = 0; i < 4; ++i) {
            const float4 qv = qr[i];
#pragma unroll
            for (int j = 0; j < 4; ++j)
                a[i][j] += qv.x * kr[j].x + qv.y * kr[j].y +
                           qv.z * kr[j].z + qv.w * kr[j].w;
            o[i][0] += qv.x * sr[0].x + qv.y * sr[1].x + qv.z * sr[2].x + qv.w * sr[3].x;
            o[i][1] += qv.x * sr[0].y + qv.y * sr[1].y + qv.z * sr[2].y + qv.w * sr[3].y;
            o[i][2] += qv.x * sr[0].z + qv.y * sr[1].z + qv.z * sr[2].z + qv.w * sr[3].z;
            o[i][3] += qv.x * sr[0].w + qv.y * sr[1].w + qv.z * sr[2].w + qv.w * sr[3].w;
            dint[i] += qv.x * z4.x + qv.y * z4.y + qv.z * z4.z + qv.w * z4.w;
        }
    }

    // causal mask + intra-chunk denominator row-sums (reduce over 16 s-tile lanes)
    float den4[4];
#pragma unroll
    for (int i = 0; i < 4; ++i) {
#pragma unroll
        for (int j = 0; j < 4; ++j)
            if (e0 + j > tt + i) a[i][j] = 0.f;
        den4[i] = a[i][0] + a[i][1] + a[i][2] + a[i][3];
    }
#pragma unroll
    for (int m = 1; m < 16; m <<= 1)
#pragma unroll
        for (int i = 0; i < 4; ++i)
            den4[i] += __shfl_xor(den4[i], m, 64);
    if ((tid & 15) == 0) {
#pragma unroll
        for (int i = 0; i < 4; ++i) denA[tt + i] = den4[i];
    }

    __syncthreads();   // everyone done reading phi(Q)/phi(K)
    // A overwrites phi(K); V (from regs) overwrites phi(Q)
#pragma unroll
    for (int i = 0; i < 4; ++i)
        *(float4*)&bufB[tt + i][e0] = make_float4(a[i][0], a[i][1], a[i][2], a[i][3]);
#pragma unroll
    for (int w = 0; w < 4; ++w) {
        const int idx = tid + (w << 8);
        *(float4*)&bufA[idx >> 4][(idx & 15) << 2] = vreg[w];
    }
    __syncthreads();

    // ---- Pass B: o += tril(A) @ V   (only s-quads <= row tile; A is masked)
    const int nq = (tt >> 2) + 1;
    for (int sq = 0; sq < nq; ++sq) {
        float4 ar[4];
#pragma unroll
        for (int i = 0; i < 4; ++i) ar[i] = *(const float4*)&bufB[tt + i][sq << 2];
#pragma unroll
        for (int ss = 0; ss < 4; ++ss) {
            const float4 vv = *(const float4*)&bufA[(sq << 2) + ss][e0];
#pragma unroll
            for (int i = 0; i < 4; ++i) {
                const float av = F4C(ar[i], ss);
                o[i][0] += av * vv.x; o[i][1] += av * vv.y;
                o[i][2] += av * vv.z; o[i][3] += av * vv.w;
            }
        }
    }

    // ---- Epilogue: divide by den, store
#pragma unroll
    for (int i = 0; i < 4; ++i) {
        const float den = dint[i] + denA[tt + i] + 1e-6f;
        const float inv = 1.0f / den;
        const int g = (((b * TT + t0 + tt + i) * HH + h) << 6) + e0;
        *(float4*)(O + g) = make_float4(o[i][0] * inv, o[i][1] * inv,
                                        o[i][2] * inv, o[i][3] * inv);
    }
}

extern "C" void kernel_launch(void* const* d_in, const int* in_sizes, int n_in,
                              void* d_out, int out_size, void* d_ws, size_t ws_size,
                              hipStream_t stream) {
    const float* q = (const float*)d_in[0];
    const float* k = (const float*)d_in[1];
    const float* v = (const float*)d_in[2];
    float* out = (float*)d_out;

    float* wsS = (float*)d_ws;                       // NCH * 64*64 floats (16 MB)
    float* wsZ = wsS + (size_t)NCH * DD * DD;        // NCH * 64 floats  (256 KB)

    k_state<<<NCH, 256, 0, stream>>>(k, v, wsS, wsZ);
    k_scan<<<520, 256, 0, stream>>>(wsS, wsZ);
    k_out<<<NCH, 256, 0, stream>>>(q, k, v, wsS, wsZ, out);
}

// Round 3
// 145.995 us; speedup vs baseline: 2.8212x; 2.8212x over previous
//
#include <hip/hip_runtime.h>

// Causal linear attention (ELU+1 feature map), chunked prefix-scan formulation.
// Shapes: q,k,v,out = [B=2, T=2048, H=16, D=64] fp32, layout [B,T,H,D].
//
// out_t = phi(q_t) . S_t / (phi(q_t) . z_t + EPS)
//   S_t = sum_{s<=t} phi(k_s)^T v_s   (D x D per (b,h))
//   z_t = sum_{s<=t} phi(k_s)
//
// Chunked (C=64): per chunk c,
//   S_prev/z_prev = exclusive prefix over chunk deltas  (phase 1 + phase 2)
//   out = (phi(Q) @ S_prev + tril(phiQ phiK^T) @ V) / (phiQ.z_prev + rowsum + EPS)
//
// R2 lesson: round-1 fused mega-loop spilled (VGPR=256, 674 MB scratch writes).
// This version serializes the passes so only ONE 4x4 accumulator is live at a
// time, writes `a` to LDS as soon as it is final, and caps VGPRs via
// __launch_bounds__(256,4).

#define BQ 2
#define TT 2048
#define HH 16
#define DD 64
#define CC 64
#define NC (TT / CC)      // 32 chunks per (b,h)
#define BH (BQ * HH)      // 32
#define NCH (BH * NC)     // 1024 chunk-blocks
#define LDP 68            // LDS row stride (floats): 16B-aligned, breaks pow2 strides

#define F4C(v, i) ((i) == 0 ? (v).x : (i) == 1 ? (v).y : (i) == 2 ? (v).z : (v).w)

__device__ __forceinline__ float phi_f(float x) {
    return x > 0.f ? x + 1.f : __expf(x);   // elu(x)+1
}

// ---------------- Phase 1: per-chunk state deltas ----------------
__global__ __launch_bounds__(256, 4) void k_state(const float* __restrict__ K,
                                                  const float* __restrict__ V,
                                                  float* __restrict__ wsS,
                                                  float* __restrict__ wsZ) {
    __shared__ float pk[CC][LDP];
    __shared__ float pv[CC][LDP];

    const int cid = blockIdx.x;
    const int bh = cid / NC, c = cid % NC;
    const int b = bh / HH, h = bh % HH;
    const int t0 = c * CC;
    const int tid = threadIdx.x;

#pragma unroll
    for (int w = 0; w < 4; ++w) {
        const int idx = tid + (w << 8);
        const int r = idx >> 4, q4 = (idx & 15) << 2;
        const int g = (((b * TT + t0 + r) * HH + h) << 6) + q4;
        float4 kv = *(const float4*)(K + g);
        kv.x = phi_f(kv.x); kv.y = phi_f(kv.y); kv.z = phi_f(kv.z); kv.w = phi_f(kv.w);
        *(float4*)&pk[r][q4] = kv;
        *(float4*)&pv[r][q4] = *(const float4*)(V + g);
    }
    __syncthreads();

    const int d0 = (tid >> 4) << 2;   // deltaS rows this thread owns
    const int e0 = (tid & 15) << 2;   // deltaS cols this thread owns
    float acc[4][4] = {};
    float zac[4] = {};
#pragma unroll 8
    for (int t = 0; t < CC; ++t) {
        const float4 a = *(const float4*)&pk[t][d0];
        const float4 vb = *(const float4*)&pv[t][e0];
        acc[0][0] += a.x * vb.x; acc[0][1] += a.x * vb.y; acc[0][2] += a.x * vb.z; acc[0][3] += a.x * vb.w;
        acc[1][0] += a.y * vb.x; acc[1][1] += a.y * vb.y; acc[1][2] += a.y * vb.z; acc[1][3] += a.y * vb.w;
        acc[2][0] += a.z * vb.x; acc[2][1] += a.z * vb.y; acc[2][2] += a.z * vb.z; acc[2][3] += a.z * vb.w;
        acc[3][0] += a.w * vb.x; acc[3][1] += a.w * vb.y; acc[3][2] += a.w * vb.z; acc[3][3] += a.w * vb.w;
        zac[0] += a.x; zac[1] += a.y; zac[2] += a.z; zac[3] += a.w;
    }

    float* S = wsS + (size_t)cid * (DD * DD);
#pragma unroll
    for (int i = 0; i < 4; ++i)
        *(float4*)(S + (d0 + i) * DD + e0) =
            make_float4(acc[i][0], acc[i][1], acc[i][2], acc[i][3]);
    if (e0 == 0)
        *(float4*)(wsZ + cid * DD + d0) = make_float4(zac[0], zac[1], zac[2], zac[3]);
}

// ---------------- Phase 2: exclusive prefix over chunks ----------------
__global__ __launch_bounds__(256) void k_scan(float* __restrict__ wsS,
                                              float* __restrict__ wsZ) {
    const int blk = blockIdx.x, tid = threadIdx.x;
    if (blk < 512) {                       // S: 32 bh * 16 segments of 256 elems
        const int bh = blk >> 4;
        const int off = ((blk & 15) << 8) + tid;
        float* p = wsS + (size_t)bh * NC * (DD * DD) + off;
        float run = 0.f;
#pragma unroll
        for (int c = 0; c < NC; ++c) {
            const float d = p[(size_t)c * (DD * DD)];
            p[(size_t)c * (DD * DD)] = run;
            run += d;
        }
    } else {                               // z: 32 bh * 64 = 2048 elems, 8 blocks
        const int zi = ((blk - 512) << 8) + tid;
        const int bh = zi >> 6, d = zi & 63;
        float* p = wsZ + bh * NC * DD + d;
        float run = 0.f;
#pragma unroll
        for (int c = 0; c < NC; ++c) {
            const float dv = p[c * DD];
            p[c * DD] = run;
            run += dv;
        }
    }
}

// ---------------- Phase 3: outputs ----------------
__global__ __launch_bounds__(256, 4) void k_out(const float* __restrict__ Q,
                                                const float* __restrict__ K,
                                                const float* __restrict__ V,
                                                const float* __restrict__ wsS,
                                                const float* __restrict__ wsZ,
                                                float* __restrict__ O) {
    __shared__ float bufA[CC][LDP];   // phi(Q), later V
    __shared__ float bufB[CC][LDP];   // phi(K), later A = tril(phiQ phiK^T)
    __shared__ float Sp[DD * DD];     // S_prev
    __shared__ float zp[DD];          // z_prev

    const int cid = blockIdx.x;
    const int bh = cid / NC, c = cid % NC;
    const int b = bh / HH, h = bh % HH;
    const int t0 = c * CC;
    const int tid = threadIdx.x;

    float4 vreg[4];                    // V staged in regs, LDS-written later (T14)
#pragma unroll
    for (int w = 0; w < 4; ++w) {
        const int idx = tid + (w << 8);
        const int r = idx >> 4, q4 = (idx & 15) << 2;
        const int g = (((b * TT + t0 + r) * HH + h) << 6) + q4;
        vreg[w] = *(const float4*)(V + g);
        float4 qv = *(const float4*)(Q + g);
        qv.x = phi_f(qv.x); qv.y = phi_f(qv.y); qv.z = phi_f(qv.z); qv.w = phi_f(qv.w);
        *(float4*)&bufA[r][q4] = qv;
        float4 kv = *(const float4*)(K + g);
        kv.x = phi_f(kv.x); kv.y = phi_f(kv.y); kv.z = phi_f(kv.z); kv.w = phi_f(kv.w);
        *(float4*)&bufB[r][q4] = kv;
    }
    {
        const float4* Sg = (const float4*)(wsS + (size_t)cid * (DD * DD));
        float4* Sl = (float4*)Sp;
#pragma unroll
        for (int w = 0; w < 4; ++w) Sl[tid + (w << 8)] = Sg[tid + (w << 8)];
        if (tid < 16) ((float4*)zp)[tid] = ((const float4*)(wsZ + cid * DD))[tid];
    }
    __syncthreads();

    const int tt = (tid >> 4) << 2;   // output row-tile base (4 rows)
    const int e0 = (tid & 15) << 2;   // output col-tile base (4 cols); s-tile in pass A

    // ---- Pass A: a[i][j] = phiQ[tt+i] . phiK[e0+j]  (ONLY accumulator live)
    float den4[4];
    {
        float a[4][4] = {};
#pragma unroll 4
        for (int d = 0; d < DD; d += 4) {
            float4 qr[4], kr[4];
#pragma unroll
            for (int i = 0; i < 4; ++i) qr[i] = *(const float4*)&bufA[tt + i][d];
#pragma unroll
            for (int j = 0; j < 4; ++j) kr[j] = *(const float4*)&bufB[e0 + j][d];
#pragma unroll
            for (int i = 0; i < 4; ++i)
#pragma unroll
                for (int j = 0; j < 4; ++j)
                    a[i][j] += qr[i].x * kr[j].x + qr[i].y * kr[j].y +
                               qr[i].z * kr[j].z + qr[i].w * kr[j].w;
        }
        // causal mask + per-row sums; butterfly leaves the FULL row-sum in all
        // 16 e-lanes, so keep it in regs (no denA LDS needed).
#pragma unroll
        for (int i = 0; i < 4; ++i) {
#pragma unroll
            for (int j = 0; j < 4; ++j)
                if (e0 + j > tt + i) a[i][j] = 0.f;
            den4[i] = a[i][0] + a[i][1] + a[i][2] + a[i][3];
        }
#pragma unroll
        for (int m = 1; m < 16; m <<= 1)
#pragma unroll
            for (int i = 0; i < 4; ++i)
                den4[i] += __shfl_xor(den4[i], m, 64);

        __syncthreads();   // all threads done reading phiK from bufB
        // retire `a` to LDS immediately (frees 16 regs before inter-chunk pass)
#pragma unroll
        for (int i = 0; i < 4; ++i)
            *(float4*)&bufB[tt + i][e0] =
                make_float4(a[i][0], a[i][1], a[i][2], a[i][3]);
    }

    // ---- Inter-chunk: o = phiQ @ S_prev, dint = phiQ . z_prev
    float o[4][4] = {};
    float dint[4] = {};
#pragma unroll 4
    for (int d = 0; d < DD; d += 4) {
        float4 qr[4], sr[4];
#pragma unroll
        for (int i = 0; i < 4; ++i) qr[i] = *(const float4*)&bufA[tt + i][d];
#pragma unroll
        for (int r = 0; r < 4; ++r) sr[r] = *(const float4*)&Sp[(d + r) * DD + e0];
        const float4 z4 = *(const float4*)&zp[d];
#pragma unroll
        for (int i = 0; i < 4; ++i) {
            const float4 qv = qr[i];
            o[i][0] += qv.x * sr[0].x + qv.y * sr[1].x + qv.z * sr[2].x + qv.w * sr[3].x;
            o[i][1] += qv.x * sr[0].y + qv.y * sr[1].y + qv.z * sr[2].y + qv.w * sr[3].y;
            o[i][2] += qv.x * sr[0].z + qv.y * sr[1].z + qv.z * sr[2].z + qv.w * sr[3].z;
            o[i][3] += qv.x * sr[0].w + qv.y * sr[1].w + qv.z * sr[2].w + qv.w * sr[3].w;
            dint[i] += qv.x * z4.x + qv.y * z4.y + qv.z * z4.z + qv.w * z4.w;
        }
    }

    __syncthreads();   // a-writes to bufB visible; everyone done reading phiQ
    // V (from regs) overwrites phiQ in bufA
#pragma unroll
    for (int w = 0; w < 4; ++w) {
        const int idx = tid + (w << 8);
        *(float4*)&bufA[idx >> 4][(idx & 15) << 2] = vreg[w];
    }
    __syncthreads();

    // ---- Pass B: o += tril(A) @ V   (only s-quads <= row tile; A is masked)
    const int nq = (tt >> 2) + 1;
    for (int sq = 0; sq < nq; ++sq) {
        float4 ar[4];
#pragma unroll
        for (int i = 0; i < 4; ++i) ar[i] = *(const float4*)&bufB[tt + i][sq << 2];
#pragma unroll
        for (int ss = 0; ss < 4; ++ss) {
            const float4 vv = *(const float4*)&bufA[(sq << 2) + ss][e0];
#pragma unroll
            for (int i = 0; i < 4; ++i) {
                const float av = F4C(ar[i], ss);
                o[i][0] += av * vv.x; o[i][1] += av * vv.y;
                o[i][2] += av * vv.z; o[i][3] += av * vv.w;
            }
        }
    }

    // ---- Epilogue: divide by den, store
#pragma unroll
    for (int i = 0; i < 4; ++i) {
        const float den = dint[i] + den4[i] + 1e-6f;
        const float inv = 1.0f / den;
        const int g = (((b * TT + t0 + tt + i) * HH + h) << 6) + e0;
        *(float4*)(O + g) = make_float4(o[i][0] * inv, o[i][1] * inv,
                                        o[i][2] * inv, o[i][3] * inv);
    }
}

extern "C" void kernel_launch(void* const* d_in, const int* in_sizes, int n_in,
                              void* d_out, int out_size, void* d_ws, size_t ws_size,
                              hipStream_t stream) {
    const float* q = (const float*)d_in[0];
    const float* k = (const float*)d_in[1];
    const float* v = (const float*)d_in[2];
    float* out = (float*)d_out;

    float* wsS = (float*)d_ws;                       // NCH * 64*64 floats (16 MB)
    float* wsZ = wsS + (size_t)NCH * DD * DD;        // NCH * 64 floats  (256 KB)

    k_state<<<NCH, 256, 0, stream>>>(k, v, wsS, wsZ);
    k_scan<<<520, 256, 0, stream>>>(wsS, wsZ);
    k_out<<<NCH, 256, 0, stream>>>(q, k, v, wsS, wsZ, out);
}